// Round 3
// baseline (301.156 us; speedup 1.0000x reference)
//
#include <hip/hip_runtime.h>

typedef unsigned short u16;
typedef __attribute__((ext_vector_type(4))) unsigned short u16x4;
typedef __attribute__((ext_vector_type(8))) __bf16 bf16x8;
typedef __attribute__((ext_vector_type(4))) float f32x4;

#define B_ 16
#define T_ 128
#define N_ 64
#define CI 128
#define CO 256

__device__ __forceinline__ u16 f2b(float f) {
    unsigned x = __builtin_bit_cast(unsigned, f);
    x += 0x7fffu + ((x >> 16) & 1u);
    return (u16)(x >> 16);
}

// ---------------- prep: M[n,o,c] = sum_k s[k,n]*dw[k,c]*Wpw[o,k*128+c]  (bf16) ----------------
__global__ void prep_kernel(const float* __restrict__ A, const float* __restrict__ dw,
                            const float* __restrict__ Wpw, const float* __restrict__ Wres,
                            u16* __restrict__ Mg, u16* __restrict__ WresB) {
    int n = blockIdx.x >> 2, ch = blockIdx.x & 3;
    int tid = threadIdx.x;
    float s0 = 0.f, s1 = 0.f, s2 = 0.f;
    for (int m = 0; m < N_; ++m) {
        s0 += A[(0 * N_ + n) * N_ + m];
        s1 += A[(1 * N_ + n) * N_ + m];
        s2 += A[(2 * N_ + n) * N_ + m];
    }
#pragma unroll
    for (int i = 0; i < 8; ++i) {
        int e4 = tid + i * 256;
        int ol = e4 >> 5, c4 = (e4 & 31) << 2;
        int o = ch * 64 + ol;
        float4 d0 = *(const float4*)(dw + c4);
        float4 d1 = *(const float4*)(dw + CI + c4);
        float4 d2 = *(const float4*)(dw + 2 * CI + c4);
        float4 p0 = *(const float4*)(Wpw + (size_t)o * 3 * CI + c4);
        float4 p1 = *(const float4*)(Wpw + (size_t)o * 3 * CI + CI + c4);
        float4 p2 = *(const float4*)(Wpw + (size_t)o * 3 * CI + 2 * CI + c4);
        u16x4 u = { f2b(s0 * d0.x * p0.x + s1 * d1.x * p1.x + s2 * d2.x * p2.x),
                    f2b(s0 * d0.y * p0.y + s1 * d1.y * p1.y + s2 * d2.y * p2.y),
                    f2b(s0 * d0.z * p0.z + s1 * d1.z * p1.z + s2 * d2.z * p2.z),
                    f2b(s0 * d0.w * p0.w + s1 * d1.w * p1.w + s2 * d2.w * p2.w) };
        *(u16x4*)(Mg + ((size_t)n << 15) + o * CI + c4) = u;
        if (n == 0) {
            float4 r = *(const float4*)(Wres + (size_t)o * CI + c4);
            u16x4 ur = { f2b(r.x), f2b(r.y), f2b(r.z), f2b(r.w) };
            *(u16x4*)(WresB + o * CI + c4) = ur;
        }
    }
}

// ---------------- fused: 16 waves/block, wave tile 32t x 64o => ~110 regs, 16 waves/CU ----------------
__global__ __launch_bounds__(1024, 4) void fused_kernel(
    const float* __restrict__ xg, const u16* __restrict__ Mg, const u16* __restrict__ WresB,
    const float* __restrict__ Wconv, const float* __restrict__ gnw, const float* __restrict__ gnb,
    const float* __restrict__ lnw, const float* __restrict__ lnb, float* __restrict__ out)
{
    __shared__ __align__(16) u16 xf[T_ * CI];          // 32 KB x in A-fragment order
    __shared__ float ebT[8][CO];                        // pre-conv rows t = {0,31,32,63,64,95,96,127}
    __shared__ float gpart[16][2][2];                   // [wave][group-half][s,q]
    __shared__ float gstat[8][2];                       // [group][mean,rstd]
    __shared__ __align__(16) float lnq[T_][18][2];      // LN partials, stride-36 padded
    __shared__ float lnstat[T_][2];                     // [t][mu,rstd]

    const int tid = threadIdx.x;
    const int bid = blockIdx.x;
    const int n = bid & 63, b = bid >> 6;               // same-n blocks share M[n] in L2 (stride-64 => same XCD)
    const float* xb = xg + (((size_t)b * T_) * N_ + n) * CI;

    // ---- stage x[b,:,n,:] -> bf16 A-fragment order ----
#pragma unroll
    for (int it = 0; it < 4; ++it) {
        int f = tid + (it << 10);
        int t = f >> 5;
        int c4 = (f & 31) << 2;
        float4 v = *(const float4*)(xb + (size_t)t * (N_ * CI) + c4);
        int kkk = c4 >> 5, quad = (c4 >> 3) & 3, j = c4 & 7;
        int mt = t >> 4;
        int sl = quad * 16 + (t & 15);
        int off = ((kkk * 8 + mt) << 9) + (sl << 3) + j;
        u16x4 u = { f2b(v.x), f2b(v.y), f2b(v.z), f2b(v.w) };
        *(u16x4*)(xf + off) = u;
    }
    __syncthreads();

    const int wid = tid >> 6, lane = tid & 63;
    const int wt = wid >> 2, wo = wid & 3;              // wave tile: t in [wt*32,+32), o in [wo*64,+64)
    const int lr = lane & 15, lq = lane >> 4;

    // ---- GEMM: ah = x.M[n]^T, ar = x.Wres^T (MFMA 16x16x32 bf16) ----
    f32x4 ah[2][4], ar[2][4];
#pragma unroll
    for (int mi = 0; mi < 2; ++mi)
#pragma unroll
        for (int ni = 0; ni < 4; ++ni) {
            ah[mi][ni] = (f32x4){0.f, 0.f, 0.f, 0.f};
            ar[mi][ni] = (f32x4){0.f, 0.f, 0.f, 0.f};
        }
    const u16* Mn = Mg + ((size_t)n << 15);
#pragma unroll
    for (int kk = 0; kk < 4; ++kk) {
        bf16x8 af[2];
#pragma unroll
        for (int mi = 0; mi < 2; ++mi)
            af[mi] = *(const bf16x8*)(xf + ((kk * 8 + wt * 2 + mi) << 9) + (lane << 3));
        const int c = kk * 32 + lq * 8;
#pragma unroll
        for (int ni = 0; ni < 4; ++ni) {
            const int o = wo * 64 + ni * 16 + lr;
            bf16x8 bm = *(const bf16x8*)(Mn + o * CI + c);
            bf16x8 br = *(const bf16x8*)(WresB + o * CI + c);
#pragma unroll
            for (int mi = 0; mi < 2; ++mi) {
                ah[mi][ni] = __builtin_amdgcn_mfma_f32_16x16x32_bf16(af[mi], bm, ah[mi][ni], 0, 0, 0);
                ar[mi][ni] = __builtin_amdgcn_mfma_f32_16x16x32_bf16(af[mi], br, ar[mi][ni], 0, 0, 0);
            }
        }
    }

    // ---- publish pre-conv boundary rows of each 32-row strip ----
    if (lq == 0) {
#pragma unroll
        for (int ni = 0; ni < 4; ++ni) ebT[wt * 2][wo * 64 + ni * 16 + lr] = ah[0][ni][0];       // t=wt*32
    }
    if (lq == 3) {
#pragma unroll
        for (int ni = 0; ni < 4; ++ni) ebT[wt * 2 + 1][wo * 64 + ni * 16 + lr] = ah[1][ni][3];   // t=wt*32+31
    }
    __syncthreads();

    // ---- depthwise conv over t IN REGISTERS + GN partials ----
    float w0[4], w1[4], w2[4];
#pragma unroll
    for (int ni = 0; ni < 4; ++ni) {
        int o = wo * 64 + ni * 16 + lr;
        w0[ni] = Wconv[o * 3 + 0];
        w1[ni] = Wconv[o * 3 + 1];
        w2[ni] = Wconv[o * 3 + 2];
    }
    float gs0 = 0.f, gq0 = 0.f, gs1 = 0.f, gq1 = 0.f;
#pragma unroll
    for (int ni = 0; ni < 4; ++ni) {
        int o = wo * 64 + ni * 16 + lr;
        float up3[2], dn0[2];
#pragma unroll
        for (int mi = 0; mi < 2; ++mi) up3[mi] = __shfl(ah[mi][ni][3], (lane + 48) & 63);
#pragma unroll
        for (int mi = 0; mi < 2; ++mi) dn0[mi] = __shfl(ah[mi][ni][0], (lane + 16) & 63);
        float epv = 0.f, env = 0.f;
        if (wt > 0) epv = ebT[wt * 2 - 1][o];           // t = wt*32 - 1
        if (wt < 3) env = ebT[wt * 2 + 2][o];           // t = wt*32 + 32
        float sA = 0.f, qA = 0.f;
#pragma unroll
        for (int mi = 0; mi < 2; ++mi) {
            float prev = (lq == 0) ? ((mi == 0) ? epv : up3[0]) : up3[mi];
            float nxt3 = (lq == 3) ? ((mi == 1) ? env : dn0[1]) : dn0[mi];
            float hm1 = prev;
#pragma unroll
            for (int e = 0; e < 4; ++e) {
                float cur = ah[mi][ni][e];
                float nx = (e < 3) ? ah[mi][ni][e + 1] : nxt3;
                float hc = w0[ni] * hm1 + w1[ni] * cur + w2[ni] * nx;
                hm1 = cur;
                ah[mi][ni][e] = hc;
                sA += hc;
                qA += hc * hc;
            }
        }
        if (ni < 2) { gs0 += sA; gq0 += qA; } else { gs1 += sA; gq1 += qA; }
    }
#pragma unroll
    for (int m = 1; m < 64; m <<= 1) {
        gs0 += __shfl_xor(gs0, m); gq0 += __shfl_xor(gq0, m);
        gs1 += __shfl_xor(gs1, m); gq1 += __shfl_xor(gq1, m);
    }
    if (lane == 0) {
        gpart[wid][0][0] = gs0; gpart[wid][0][1] = gq0;
        gpart[wid][1][0] = gs1; gpart[wid][1][1] = gq1;
    }
    __syncthreads();
    if (tid < 8) {                                      // group g: waves wt*4 + (g>>1), slot g&1
        int wg = tid >> 1, hf = tid & 1;
        float s = gpart[wg][hf][0] + gpart[4 + wg][hf][0] + gpart[8 + wg][hf][0] + gpart[12 + wg][hf][0];
        float q = gpart[wg][hf][1] + gpart[4 + wg][hf][1] + gpart[8 + wg][hf][1] + gpart[12 + wg][hf][1];
        float mu = s * (1.f / 4096.f);
        float var = q * (1.f / 4096.f) - mu * mu;
        gstat[tid][0] = mu;
        gstat[tid][1] = rsqrtf(var + 1e-5f);
    }
    __syncthreads();

    // ---- v = hc*gn + residual (regs), LN partials: 2-level shfl + LDS transpose ----
    float gwm[4], gbm[4], lw[4], lb[4];
#pragma unroll
    for (int ni = 0; ni < 4; ++ni) {
        int o = wo * 64 + ni * 16 + lr;
        lw[ni] = lnw[o]; lb[ni] = lnb[o];
        float mg = gstat[wo * 2 + (ni >> 1)][0];
        float rg = gstat[wo * 2 + (ni >> 1)][1];
        gwm[ni] = gnw[o] * rg;
        gbm[ni] = gnb[o] - mg * gwm[ni];
    }
#pragma unroll
    for (int mi = 0; mi < 2; ++mi)
#pragma unroll
        for (int e = 0; e < 4; ++e) {
            float s = 0.f, q = 0.f;
#pragma unroll
            for (int ni = 0; ni < 4; ++ni) {
                float v = ah[mi][ni][e] * gwm[ni] + gbm[ni] + ar[mi][ni][e];
                ah[mi][ni][e] = v;
                s += v; q += v * v;
            }
            s += __shfl_xor(s, 1); q += __shfl_xor(q, 1);
            s += __shfl_xor(s, 2); q += __shfl_xor(q, 2);
            if ((lr & 3) == 0) {
                int t = wt * 32 + mi * 16 + lq * 4 + e;
                int j = (lr >> 2) * 4 + wo;
                *(float2*)&lnq[t][j][0] = make_float2(s, q);
            }
        }
    __syncthreads();
    {
        int t = tid >> 3, p = tid & 7;                  // 8 threads per t, each sums 2 of 16 slots
        f32x4 v4 = *(const f32x4*)&lnq[t][2 * p][0];
        float s = v4.x + v4.z, q = v4.y + v4.w;
        s += __shfl_xor(s, 1); q += __shfl_xor(q, 1);
        s += __shfl_xor(s, 2); q += __shfl_xor(q, 2);
        s += __shfl_xor(s, 4); q += __shfl_xor(q, 4);
        if (p == 0) {
            float mu = s * (1.f / 256.f);
            float var = q * (1.f / 256.f) - mu * mu;
            lnstat[t][0] = mu;
            lnstat[t][1] = rsqrtf(var + 1e-5f);
        }
    }
    __syncthreads();

    // ---- finalize: LN + exact GELU + store ----
    float* ob = out + (((size_t)b * T_ + wt * 32) * N_ + n) * CO + wo * 64;
#pragma unroll
    for (int mi = 0; mi < 2; ++mi)
#pragma unroll
        for (int e = 0; e < 4; ++e) {
            int tl = mi * 16 + lq * 4 + e;
            float mu = lnstat[wt * 32 + tl][0];
            float rs = lnstat[wt * 32 + tl][1];
#pragma unroll
            for (int ni = 0; ni < 4; ++ni) {
                float u = (ah[mi][ni][e] - mu) * rs * lw[ni] + lb[ni];
                float ge = 0.5f * u * (1.f + erff(u * 0.70710678118654752f));
                ob[(size_t)tl * (N_ * CO) + ni * 16 + lr] = ge;
            }
        }
}

extern "C" void kernel_launch(void* const* d_in, const int* in_sizes, int n_in,
                              void* d_out, int out_size, void* d_ws, size_t ws_size,
                              hipStream_t stream) {
    const float* x    = (const float*)d_in[0];
    const float* A    = (const float*)d_in[1];
    const float* dw   = (const float*)d_in[2];
    const float* Wpw  = (const float*)d_in[3];
    const float* Wcv  = (const float*)d_in[4];
    const float* gnw  = (const float*)d_in[5];
    const float* gnb  = (const float*)d_in[6];
    const float* lnw  = (const float*)d_in[7];
    const float* lnb  = (const float*)d_in[8];
    const float* Wres = (const float*)d_in[9];

    u16* Mg    = (u16*)d_ws;                          // 64*256*128 bf16 = 4MB
    u16* WresB = Mg + (size_t)N_ * CO * CI;           // 256*128 bf16 = 64KB

    prep_kernel<<<N_ * 4, 256, 0, stream>>>(A, dw, Wpw, Wres, Mg, WresB);
    fused_kernel<<<B_ * N_, 1024, 0, stream>>>(x, Mg, WresB, Wcv, gnw, gnb, lnw, lnb, (float*)d_out);
}